// Round 8
// baseline (20811.995 us; speedup 1.0000x reference)
//
#include <hip/hip_runtime.h>

// per-batch NCHW fp32 planes in ws; total 55,312,384 B
#define OFF_INP 0ull
#define OFF_H   30146560ull    // 115*65536*4
#define OFF_T1  38535168ull    // +32*65536*4
#define OFF_FEA 46923776ull    // +32*65536*4
#define WS_NEED 55312384ull

__device__ __forceinline__ float lrelu(float x){ return x >= 0.f ? x : 0.1f * x; }

// ---- sentinel: encode an interface mismatch into out[0] (read via absmax printout) ----
__global__ void k_sent(float* __restrict__ out, float val){
  if (threadIdx.x == 0 && blockIdx.x == 0) out[0] = val;
}

// ---- correlation: thread = (pixel, dy). inp plane ch = dy*9+dx, value lrelu(mean_c ref*nb) ----
__global__ __launch_bounds__(256) void k_corr6(const float* __restrict__ xref,
    const float* __restrict__ xnb, float* __restrict__ inp, int b){
  int idx = blockIdx.x * 256 + threadIdx.x;
  if (idx >= 9 * 65536) return;
  int dy = idx >> 16;
  int p  = idx & 65535;
  int y = p >> 8, x = p & 255;
  const float* rbase = xref + (size_t)b * 2097152 + p;     // stride 65536 per channel
  int iy = y + dy - 4;
  for (int dx = 0; dx < 9; dx++){
    int ix = x + dx - 4;
    float s = 0.f;
    if (iy >= 0 && iy < 256 && ix >= 0 && ix < 256){
      const float* nbase = xnb + (size_t)b * 2097152 + iy * 256 + ix;
      for (int c = 0; c < 32; c++)
        s = fmaf(rbase[(size_t)c * 65536], nbase[(size_t)c * 65536], s);
    }
    inp[(size_t)(dy * 9 + dx) * 65536 + p] = lrelu(s / 32.f);
  }
}

// ---- bilinear 2x upsample (half-pixel via floorf), inp planes 81..114 ----
__global__ __launch_bounds__(256) void k_up6(const float* __restrict__ bflow,
    const float* __restrict__ bfeat, float* __restrict__ inp, int b){
  int p = blockIdx.x * 256 + threadIdx.x;
  if (p >= 65536) return;
  int y = p >> 8, x = p & 255;
  float sy = 0.5f * (float)y - 0.25f;
  float sx = 0.5f * (float)x - 0.25f;
  int y0 = (int)floorf(sy), x0 = (int)floorf(sx);
  float fy = sy - (float)y0, fx = sx - (float)x0;
  int ya = y0 < 0 ? 0 : y0;           int xa = x0 < 0 ? 0 : x0;
  int yb = y0 + 1 > 127 ? 127 : y0+1; int xb = x0 + 1 > 127 ? 127 : x0+1;
  for (int cu = 0; cu < 34; cu++){
    const float* pl = (cu < 32) ? (bfeat + ((size_t)b * 32 + cu) * 16384)
                                : (bflow + ((size_t)b * 2 + (cu - 32)) * 16384);
    float v00 = pl[ya * 128 + xa], v01 = pl[ya * 128 + xb];
    float v10 = pl[yb * 128 + xa], v11 = pl[yb * 128 + xb];
    float top = v00 * (1.f - fx) + v01 * fx;
    float bot = v10 * (1.f - fx) + v11 * fx;
    float v = top * (1.f - fy) + bot * fy;
    if (cu >= 32) v *= 2.f;
    inp[(size_t)(81 + cu) * 65536 + p] = v;
  }
}

// ---- generic scalar 3x3 SAME conv on NCHW fp32 planes ----
// MODE 0: conv0 115->32, lrelu -> h.  MODE 1: conv1 32->32, lrelu -> t1.
// MODE 2: conv2 32->32, +h resid, lrelu -> fea plane AND fp32 feats out.
// MODE 3: convf 32->3 -> flows fp32 (co 0,1), sigmoid mask fp32 (co 2).
template<int CI, int MODE>
__global__ __launch_bounds__(256) void k_conv6(const float* __restrict__ in,
    const float* __restrict__ w, const float* __restrict__ bs,
    float* __restrict__ outp, const float* __restrict__ resid,
    float* __restrict__ outw, int b){
  int idx = blockIdx.x * 256 + threadIdx.x;
  int co, p;
  if constexpr (MODE == 3){
    if (idx >= 4 * 65536) return;
    co = idx & 3; p = idx >> 2;
    if (co == 3) return;
  } else {
    if (idx >= 32 * 65536) return;
    co = idx & 31; p = idx >> 5;
  }
  int y = p >> 8, x = p & 255;
  float acc = bs[co];
  for (int ci = 0; ci < CI; ci++){
    const float* plane = in + (size_t)ci * 65536;
    const float* wp = w + ((size_t)co * CI + ci) * 9;
    for (int ky = 0; ky < 3; ky++){
      int iy = y + ky - 1;
      if (iy < 0 || iy > 255) continue;
      for (int kx = 0; kx < 3; kx++){
        int ix = x + kx - 1;
        if (ix < 0 || ix > 255) continue;
        acc = fmaf(plane[iy * 256 + ix], wp[ky * 3 + kx], acc);
      }
    }
  }
  if constexpr (MODE == 0){
    outp[(size_t)co * 65536 + p] = lrelu(acc);
  } else if constexpr (MODE == 1){
    outp[(size_t)co * 65536 + p] = lrelu(acc);
  } else if constexpr (MODE == 2){
    float v = lrelu(acc + resid[(size_t)co * 65536 + p]);
    outp[(size_t)co * 65536 + p] = v;
    outw[786432 + ((size_t)b * 32 + co) * 65536 + p] = v;           // feats out
  } else {
    if (co < 2){
      outw[((size_t)b * 2 + co) * 65536 + p] = acc;                 // flows out
    } else {
      float s = 1.f / (1.f + expf(-acc));
      outw[524288 + (size_t)b * 65536 + p] = s;                     // mask out
    }
  }
}

extern "C" void kernel_launch(void* const* d_in, const int* in_sizes, int n_in,
                              void* d_out, int out_size, void* d_ws, size_t ws_size,
                              hipStream_t stream){
  float* out = (float*)d_out;

  // ---- runtime interface verification (host-side; sentinel encodes any mismatch) ----
  static const int exp_sizes[12] = {8388608, 8388608, 131072, 2097152,
                                    33120, 32, 9216, 32, 9216, 32, 864, 3};
  float sent = 0.f;
  if (n_in != 12) sent = 1.0e6f;
  else if (out_size != 9175040) sent = 2.0e6f;
  else {
    for (int i = 0; i < 12; i++)
      if (in_sizes[i] != exp_sizes[i]){ sent = 3.0e6f * (1.0f + 0.01f * i); break; }
    if (sent == 0.f && ws_size < WS_NEED)
      sent = 16.0f * (float)(ws_size >> 20);
  }
  if (sent != 0.f){
    hipLaunchKernelGGL(k_sent, dim3(1), dim3(64), 0, stream, out, sent);
    return;
  }

  const float* xref  = (const float*)d_in[0];
  const float* xnb   = (const float*)d_in[1];
  const float* bflow = (const float*)d_in[2];
  const float* bfeat = (const float*)d_in[3];
  const float* w0 = (const float*)d_in[4];
  const float* b0 = (const float*)d_in[5];
  const float* w1 = (const float*)d_in[6];
  const float* b1 = (const float*)d_in[7];
  const float* w2 = (const float*)d_in[8];
  const float* b2 = (const float*)d_in[9];
  const float* wf = (const float*)d_in[10];
  const float* bf = (const float*)d_in[11];
  char* ws = (char*)d_ws;
  float* inp = (float*)(ws + OFF_INP);
  float* h   = (float*)(ws + OFF_H);
  float* t1  = (float*)(ws + OFF_T1);
  float* fea = (float*)(ws + OFF_FEA);

  for (int b = 0; b < 4; b++){
    hipLaunchKernelGGL(k_corr6, dim3(2304), dim3(256), 0, stream, xref, xnb, inp, b);
    hipLaunchKernelGGL(k_up6, dim3(256), dim3(256), 0, stream, bflow, bfeat, inp, b);
    hipLaunchKernelGGL((k_conv6<115, 0>), dim3(8192), dim3(256), 0, stream,
                       inp, w0, b0, h, (const float*)nullptr, out, b);
    hipLaunchKernelGGL((k_conv6<32, 1>), dim3(8192), dim3(256), 0, stream,
                       h, w1, b1, t1, (const float*)nullptr, out, b);
    hipLaunchKernelGGL((k_conv6<32, 2>), dim3(8192), dim3(256), 0, stream,
                       t1, w2, b2, fea, h, out, b);
    hipLaunchKernelGGL((k_conv6<32, 3>), dim3(1024), dim3(256), 0, stream,
                       fea, wf, bf, (float*)nullptr, (const float*)nullptr, out, b);
  }
}

// Round 9
// 732.808 us; speedup vs baseline: 28.4003x; 28.4003x over previous
//
#include <hip/hip_runtime.h>

typedef unsigned short u16;
typedef unsigned int u32;
typedef __bf16 bf16x8 __attribute__((ext_vector_type(8)));
typedef float f32x4 __attribute__((ext_vector_type(4)));

#define HP 258
// weight-table element offsets within ws (u16 units)
#define E_WT0 0
#define E_WT1 37120
#define E_WT2 46592
#define E_WTF 56064
// per-batch tensor byte offsets within ws (total footprint 29,951,744 B; ws >= 55.3 MB verified R6/R8)
#define OFF_INPT 131072ull
#define OFF_HT   17171456ull   // OFF_INPT + 258*258*128*2
#define OFF_T1   21431552ull   // OFF_HT + 258*258*32*2
#define OFF_FEA  25691648ull   // OFF_T1 + 258*258*32*2
#define WS_NEED  29951744ull

__device__ __forceinline__ float bf2f(u16 u){ u32 x = ((u32)u) << 16; return __builtin_bit_cast(float, x); }
__device__ __forceinline__ u16 f2bf(float f){
  u32 x = __builtin_bit_cast(u32, f);
  return (u16)((x + 0x7fffu + ((x >> 16) & 1u)) >> 16);   // RNE
}
__device__ __forceinline__ u32 pack2(float a, float b){ return (u32)f2bf(a) | ((u32)f2bf(b) << 16); }
__device__ __forceinline__ float lrelu(float x){ return x >= 0.f ? x : 0.1f * x; }

__global__ void k_sent(float* __restrict__ out, float val){
  if (threadIdx.x == 0 && blockIdx.x == 0) out[0] = val;
}

// ---------------- halo-ring zeroing for all four per-batch buffers (once per launch) ----------
__global__ __launch_bounds__(256) void k_halo(char* __restrict__ ws){
  int idx = blockIdx.x * 256 + threadIdx.x;
  if (idx >= 258 * 258) return;
  int y = idx / 258;
  int x = idx - y * 258;
  if (y != 0 && y != 257 && x != 0 && x != 257) return;
  uint4 z = make_uint4(0u, 0u, 0u, 0u);
  size_t pix = (size_t)idx;
  uint4* p0 = (uint4*)(ws + OFF_INPT + pix * 256);
  #pragma unroll
  for (int k = 0; k < 16; k++) p0[k] = z;
  uint4* p1 = (uint4*)(ws + OFF_HT + pix * 64);
  uint4* p2 = (uint4*)(ws + OFF_T1 + pix * 64);
  uint4* p3 = (uint4*)(ws + OFF_FEA + pix * 64);
  #pragma unroll
  for (int k = 0; k < 4; k++){ p1[k] = z; p2[k] = z; p3[k] = z; }
}

// ---------------- weight re-layout: Wt[co][tap*Cpad + c], tap-major K, channel-permuted -------
// inpT channel order: 0..31 up-feat, 32..33 flow, 34..114 corr(dy*9+dx), 115..127 zero.
// Original (R8-verified) w0 input-channel order: 0..80 corr, 81..112 feat, 113..114 flow.
__global__ __launch_bounds__(256) void k_wprep(const float* __restrict__ w0, const float* __restrict__ w1,
    const float* __restrict__ w2, const float* __restrict__ wf, u16* __restrict__ wse){
  for (int idx = blockIdx.x * 256 + threadIdx.x; idx < 60800; idx += 64 * 256){
    float v = 0.f;
    if (idx < 37120){                       // Wt0: 32 rows x 1160 (K=9*128=1152 used)
      int co = idx / 1160, kk = idx % 1160;
      if (kk < 1152){
        int tap = kk >> 7, c = kk & 127;
        if (c < 115){
          int oc = (c < 34) ? (81 + c) : (c - 34);
          v = w0[(co * 115 + oc) * 9 + tap];
        }
      }
    } else if (idx < 46592){                // Wt1: 32 x 296 (K=9*32=288)
      int r = idx - 37120; int co = r / 296, kk = r % 296;
      if (kk < 288){ int tap = kk >> 5, c = kk & 31; v = w1[(co * 32 + c) * 9 + tap]; }
    } else if (idx < 56064){                // Wt2
      int r = idx - 46592; int co = r / 296, kk = r % 296;
      if (kk < 288){ int tap = kk >> 5, c = kk & 31; v = w2[(co * 32 + c) * 9 + tap]; }
    } else {                                // Wtf: 16 x 296, rows 3..15 zero
      int r = idx - 56064; int co = r / 296, kk = r % 296;
      if (kk < 288 && co < 3){ int tap = kk >> 5, c = kk & 31; v = wf[(co * 32 + c) * 9 + tap]; }
    }
    wse[idx] = f2bf(v);
  }
}

// ---------------- fused correlation + 2x bilinear upsample -> inpT [258][258][128] bf16 -------
__global__ __launch_bounds__(64) void k_corr_up(
    const float* __restrict__ xref, const float* __restrict__ xnb,
    const float* __restrict__ bflow, const float* __restrict__ bfeat,
    char* __restrict__ ws, int bio){
  __shared__ __align__(16) u16 refL[32][256];
  __shared__ __align__(16) u16 nbL[32][272];   // lds col = img col + 8 ; stride 544 B
  const int t = threadIdx.x;
  const int bx = blockIdx.x;
  const int h = (bx & 7) * 32 + (bx >> 3);     // XCD swizzle: 32-row bands per XCD
  const int w0 = t * 4;

  // stage ref row (32 ch x 256 px), fp32 -> bf16
  #pragma unroll
  for (int k = 0; k < 32; k++){
    int id = t + 64 * k; int c = id >> 6, ck = id & 63;
    float4 v = ((const float4*)(xref + ((size_t)(bio * 32 + c)) * 65536 + (size_t)h * 256))[ck];
    ushort4 s = make_ushort4(f2bf(v.x), f2bf(v.y), f2bf(v.z), f2bf(v.w));
    *((ushort4*)&refL[c][ck * 4]) = s;
  }
  __syncthreads();

  size_t pxb[4];
  #pragma unroll
  for (int p = 0; p < 4; p++)
    pxb[p] = OFF_INPT + ((size_t)(h + 1) * 258 + (w0 + p + 1)) * 256;

  // ---- channels 0..33: bilinear 2x upsample (half-pixel, edge clamp), flow *2 ----
  {
    int y0 = (h >> 1) - 1 + (h & 1);
    float fyv = (h & 1) ? 0.25f : 0.75f;
    int y0c = y0 < 0 ? 0 : y0;
    int y1c = (y0 + 1) > 127 ? 127 : (y0 + 1);
    int y0o = y0c * 128, y1o = y1c * 128;
    int x0c[4], x1c[4]; float fxv[4];
    #pragma unroll
    for (int p = 0; p < 4; p++){
      int w = w0 + p; int x0 = (w >> 1) - 1 + (w & 1);
      fxv[p] = (w & 1) ? 0.25f : 0.75f;
      x0c[p] = x0 < 0 ? 0 : x0;
      x1c[p] = (x0 + 1) > 127 ? 127 : (x0 + 1);
    }
    for (int d = 0; d < 17; d++){
      #pragma unroll
      for (int p = 0; p < 4; p++){
        float vv[2];
        #pragma unroll
        for (int e = 0; e < 2; e++){
          int c = 2 * d + e;
          const float* pl = (c < 32) ? (bfeat + ((size_t)(bio * 32 + c)) * 16384)
                                     : (bflow + ((size_t)(bio * 2 + (c - 32))) * 16384);
          float v00 = pl[y0o + x0c[p]], v01 = pl[y0o + x1c[p]];
          float v10 = pl[y1o + x0c[p]], v11 = pl[y1o + x1c[p]];
          float r0 = v00 + fxv[p] * (v01 - v00);
          float r1 = v10 + fxv[p] * (v11 - v10);
          float v = r0 + fyv * (r1 - r0);
          vv[e] = (c >= 32) ? v * 2.f : v;
        }
        *(u32*)(ws + pxb[p] + 4 * d) = pack2(vv[0], vv[1]);
      }
    }
  }

  // ---- correlation: 81 channels, processed in dy pairs for aligned dword stores ----
  #pragma unroll
  for (int P = 0; P < 5; P++){
    float acc[18][4];
    #pragma unroll
    for (int a = 0; a < 18; a++)
      #pragma unroll
      for (int p = 0; p < 4; p++) acc[a][p] = 0.f;
    const int ndy = (P < 4) ? 2 : 1;
    #pragma unroll
    for (int dyh = 0; dyh < ndy; dyh++){
      const int dy = 2 * P + dyh;
      const int ih = h + dy - 4;
      __syncthreads();          // previous-iteration readers done
      {                         // zero halo cols (img -8..-1 and 256..263)
        uint4 z = make_uint4(0u, 0u, 0u, 0u);
        if (t < 32) *((uint4*)&nbL[t][0]) = z;
        else        *((uint4*)&nbL[t - 32][264]) = z;
      }
      const bool oob = (ih < 0) || (ih > 255);
      #pragma unroll
      for (int k = 0; k < 32; k++){
        int id = t + 64 * k; int c = id >> 6, ck = id & 63;
        ushort4 s = make_ushort4(0, 0, 0, 0);
        if (!oob){
          float4 v = ((const float4*)(xnb + ((size_t)(bio * 32 + c)) * 65536 + (size_t)ih * 256))[ck];
          s = make_ushort4(f2bf(v.x), f2bf(v.y), f2bf(v.z), f2bf(v.w));
        }
        *((ushort4*)&nbL[c][8 + ck * 4]) = s;
      }
      __syncthreads();
      #pragma unroll 2
      for (int c = 0; c < 32; c++){
        uint2 wa = *(const uint2*)&nbL[c][w0 + 4];
        uint2 wb = *(const uint2*)&nbL[c][w0 + 8];
        uint2 wc = *(const uint2*)&nbL[c][w0 + 12];
        float win[12];
        win[0] = bf2f((u16)(wa.x & 0xffff)); win[1] = bf2f((u16)(wa.x >> 16));
        win[2] = bf2f((u16)(wa.y & 0xffff)); win[3] = bf2f((u16)(wa.y >> 16));
        win[4] = bf2f((u16)(wb.x & 0xffff)); win[5] = bf2f((u16)(wb.x >> 16));
        win[6] = bf2f((u16)(wb.y & 0xffff)); win[7] = bf2f((u16)(wb.y >> 16));
        win[8] = bf2f((u16)(wc.x & 0xffff)); win[9] = bf2f((u16)(wc.x >> 16));
        win[10] = bf2f((u16)(wc.y & 0xffff)); win[11] = bf2f((u16)(wc.y >> 16));
        uint2 rr = *(const uint2*)&refL[c][w0];
        float rv[4] = { bf2f((u16)(rr.x & 0xffff)), bf2f((u16)(rr.x >> 16)),
                        bf2f((u16)(rr.y & 0xffff)), bf2f((u16)(rr.y >> 16)) };
        #pragma unroll
        for (int dx = 0; dx < 9; dx++)
          #pragma unroll
          for (int p = 0; p < 4; p++)
            acc[dyh * 9 + dx][p] = fmaf(rv[p], win[p + dx], acc[dyh * 9 + dx][p]);
      }
    }
    // store: corr value = lrelu(acc/32); inpT channel 34 + dy*9 + dx
    if (P < 4){
      #pragma unroll
      for (int p = 0; p < 4; p++)
        #pragma unroll
        for (int d = 0; d < 9; d++){
          float lo = lrelu(acc[2 * d][p] * 0.03125f);
          float hi = lrelu(acc[2 * d + 1][p] * 0.03125f);
          *(u32*)(ws + pxb[p] + 68 + 36 * P + 4 * d) = pack2(lo, hi);
        }
    } else {
      #pragma unroll
      for (int p = 0; p < 4; p++)
        #pragma unroll
        for (int d = 0; d < 11; d++){
          float lo = (2 * d < 9)     ? lrelu(acc[2 * d][p] * 0.03125f)     : 0.f;
          float hi = (2 * d + 1 < 9) ? lrelu(acc[2 * d + 1][p] * 0.03125f) : 0.f;
          *(u32*)(ws + pxb[p] + 212 + 4 * d) = pack2(lo, hi);   // ch 106..114 + zero pad to 127
        }
    }
  }
}

// ---------------- conv0: 128->32, MFMA implicit GEMM, weights LDS-chunked ---------------------
__global__ __launch_bounds__(256) void k_conv0(const u16* __restrict__ inT, const u16* __restrict__ wt,
    const float* __restrict__ bias, u16* __restrict__ outA){
  __shared__ __align__(16) u16 wl[32 * 648];
  const int tid = threadIdx.x;
  const int bx = blockIdx.x;
  const int row = (bx & 7) * 32 + (bx >> 3);
  const int wv = tid >> 6, ln = tid & 63, l15 = ln & 15, l4 = ln >> 4;
  f32x4 acc[4][2] = {};
  const u16* aB[4];
  #pragma unroll
  for (int i = 0; i < 4; i++)
    aB[i] = inT + (size_t)(row * HP + (wv * 64 + i * 16 + l15)) * 128 + l4 * 8;

  // chunk 0: taps 0..3 (512 k-elems/row)
  for (int i = tid; i < 2048; i += 256){
    int co = i >> 6, q = i & 63;
    ((uint4*)&wl[co * 648])[q] = *(const uint4*)&wt[co * 1160 + q * 8];
  }
  __syncthreads();
  #pragma unroll
  for (int tap = 0; tap < 4; tap++){
    const int ky = tap / 3, kx = tap % 3;
    #pragma unroll
    for (int s = 0; s < 4; s++){
      bf16x8 bv[2];
      #pragma unroll
      for (int j = 0; j < 2; j++){
        uint4 u = *(const uint4*)&wl[(j * 16 + l15) * 648 + tap * 128 + s * 32 + l4 * 8];
        bv[j] = __builtin_bit_cast(bf16x8, u);
      }
      #pragma unroll
      for (int i = 0; i < 4; i++){
        uint4 ua = *(const uint4*)(aB[i] + (ky * HP + kx) * 128 + s * 32);
        bf16x8 av = __builtin_bit_cast(bf16x8, ua);
        #pragma unroll
        for (int j = 0; j < 2; j++)
          acc[i][j] = __builtin_amdgcn_mfma_f32_16x16x32_bf16(av, bv[j], acc[i][j], 0, 0, 0);
      }
    }
  }
  __syncthreads();
  // chunk 1: taps 4..8 (640 k-elems/row)
  for (int i = tid; i < 2560; i += 256){
    int co = i / 80, q = i % 80;
    ((uint4*)&wl[co * 648])[q] = *(const uint4*)&wt[co * 1160 + 512 + q * 8];
  }
  __syncthreads();
  #pragma unroll
  for (int tap = 4; tap < 9; tap++){
    const int ky = tap / 3, kx = tap % 3;
    #pragma unroll
    for (int s = 0; s < 4; s++){
      bf16x8 bv[2];
      #pragma unroll
      for (int j = 0; j < 2; j++){
        uint4 u = *(const uint4*)&wl[(j * 16 + l15) * 648 + (tap - 4) * 128 + s * 32 + l4 * 8];
        bv[j] = __builtin_bit_cast(bf16x8, u);
      }
      #pragma unroll
      for (int i = 0; i < 4; i++){
        uint4 ua = *(const uint4*)(aB[i] + (ky * HP + kx) * 128 + s * 32);
        bf16x8 av = __builtin_bit_cast(bf16x8, ua);
        #pragma unroll
        for (int j = 0; j < 2; j++)
          acc[i][j] = __builtin_amdgcn_mfma_f32_16x16x32_bf16(av, bv[j], acc[i][j], 0, 0, 0);
      }
    }
  }
  // epilogue: bias + lrelu -> hT halo layout (bf16)
  #pragma unroll
  for (int i = 0; i < 4; i++){
    const int pxb = wv * 64 + i * 16 + l4 * 4;
    #pragma unroll
    for (int j = 0; j < 2; j++){
      const int co = j * 16 + l15;
      const float bs = bias[co];
      #pragma unroll
      for (int r = 0; r < 4; r++){
        const int px = pxb + r;
        float v = lrelu(acc[i][j][r] + bs);
        outA[(size_t)((row + 1) * HP + px + 1) * 32 + co] = f2bf(v);
      }
    }
  }
}

// ---------------- 32-cin convs (conv1/conv2/convf), MFMA -------------------------------------
// MODE 0: bias+lrelu -> halo outH (t1). MODE 1: +resid, lrelu -> halo outH (fea) AND fp32 out feats.
// MODE 2: flows (co 0,1) + sigmoid mask (co 2) -> fp32 out.
template<int NT, int MODE>
__global__ __launch_bounds__(256) void k_conv32(const u16* __restrict__ inT, const u16* __restrict__ wt,
    const float* __restrict__ bias, u16* __restrict__ outH, float* __restrict__ outF,
    const u16* __restrict__ resid, int bio){
  constexpr int NR = (NT == 2) ? 32 : 16;
  __shared__ __align__(16) u16 wl[NR * 296];
  const int tid = threadIdx.x;
  for (int i = tid; i < NR * 296 / 8; i += 256)
    ((uint4*)wl)[i] = ((const uint4*)wt)[i];
  __syncthreads();
  const int bx = blockIdx.x;
  const int row = (bx & 7) * 32 + (bx >> 3);
  const int wv = tid >> 6, ln = tid & 63, l15 = ln & 15, l4 = ln >> 4;
  f32x4 acc[4][NT] = {};
  const u16* aB[4];
  #pragma unroll
  for (int i = 0; i < 4; i++)
    aB[i] = inT + (size_t)(row * HP + (wv * 64 + i * 16 + l15)) * 32 + l4 * 8;
  #pragma unroll
  for (int ky = 0; ky < 3; ky++){
    #pragma unroll
    for (int kx = 0; kx < 3; kx++){
      const int tap = ky * 3 + kx;
      bf16x8 bv[NT];
      #pragma unroll
      for (int j = 0; j < NT; j++){
        uint4 u = *(const uint4*)&wl[(j * 16 + l15) * 296 + tap * 32 + l4 * 8];
        bv[j] = __builtin_bit_cast(bf16x8, u);
      }
      #pragma unroll
      for (int i = 0; i < 4; i++){
        uint4 ua = *(const uint4*)(aB[i] + (ky * HP + kx) * 32);
        bf16x8 av = __builtin_bit_cast(bf16x8, ua);
        #pragma unroll
        for (int j = 0; j < NT; j++)
          acc[i][j] = __builtin_amdgcn_mfma_f32_16x16x32_bf16(av, bv[j], acc[i][j], 0, 0, 0);
      }
    }
  }
  #pragma unroll
  for (int i = 0; i < 4; i++){
    const int pxb = wv * 64 + i * 16 + l4 * 4;
    #pragma unroll
    for (int j = 0; j < NT; j++){
      const int co = j * 16 + l15;
      float bs;
      if constexpr (MODE == 2) bs = (co < 3) ? bias[co] : 0.f;
      else bs = bias[co];
      #pragma unroll
      for (int r = 0; r < 4; r++){
        const int px = pxb + r;
        float v = acc[i][j][r] + bs;
        if constexpr (MODE == 0){
          v = lrelu(v);
          outH[(size_t)((row + 1) * HP + px + 1) * 32 + co] = f2bf(v);
        } else if constexpr (MODE == 1){
          float hres = bf2f(resid[(size_t)((row + 1) * HP + px + 1) * 32 + co]);
          v = lrelu(v + hres);
          outH[(size_t)((row + 1) * HP + px + 1) * 32 + co] = f2bf(v);                  // feaT
          outF[786432 + ((size_t)(bio * 32 + co)) * 65536 + (size_t)row * 256 + px] = v; // feats
        } else {
          if (co < 2)
            outF[((size_t)(bio * 2 + co)) * 65536 + (size_t)row * 256 + px] = v;        // flows
          else if (co == 2){
            float s = 1.f / (1.f + __expf(-v));
            outF[524288 + (size_t)bio * 65536 + (size_t)row * 256 + px] = s;            // mask
          }
        }
      }
    }
  }
}

extern "C" void kernel_launch(void* const* d_in, const int* in_sizes, int n_in,
                              void* d_out, int out_size, void* d_ws, size_t ws_size,
                              hipStream_t stream){
  float* out = (float*)d_out;

  // ---- runtime interface verification (kept from R6; encodes any mismatch into out[0]) ----
  static const int exp_sizes[12] = {8388608, 8388608, 131072, 2097152,
                                    33120, 32, 9216, 32, 9216, 32, 864, 3};
  float sent = 0.f;
  if (n_in != 12) sent = 1.0e6f;
  else if (out_size != 9175040) sent = 2.0e6f;
  else {
    for (int i = 0; i < 12; i++)
      if (in_sizes[i] != exp_sizes[i]){ sent = 3.0e6f * (1.0f + 0.01f * i); break; }
    if (sent == 0.f && ws_size < WS_NEED)
      sent = 16.0f * (float)(ws_size >> 20);
  }
  if (sent != 0.f){
    hipLaunchKernelGGL(k_sent, dim3(1), dim3(64), 0, stream, out, sent);
    return;
  }

  const float* xref  = (const float*)d_in[0];
  const float* xnb   = (const float*)d_in[1];
  const float* bflow = (const float*)d_in[2];
  const float* bfeat = (const float*)d_in[3];
  const float* w0 = (const float*)d_in[4];
  const float* b0 = (const float*)d_in[5];
  const float* w1 = (const float*)d_in[6];
  const float* b1 = (const float*)d_in[7];
  const float* w2 = (const float*)d_in[8];
  const float* b2 = (const float*)d_in[9];
  const float* wf = (const float*)d_in[10];
  const float* bf = (const float*)d_in[11];
  char* ws = (char*)d_ws;
  u16* wse  = (u16*)d_ws;
  u16* inpT = (u16*)(ws + OFF_INPT);
  u16* hT   = (u16*)(ws + OFF_HT);
  u16* t1T  = (u16*)(ws + OFF_T1);
  u16* feaT = (u16*)(ws + OFF_FEA);

  hipLaunchKernelGGL(k_halo, dim3(261), dim3(256), 0, stream, ws);
  hipLaunchKernelGGL(k_wprep, dim3(64), dim3(256), 0, stream, w0, w1, w2, wf, wse);
  for (int bio = 0; bio < 4; bio++){
    hipLaunchKernelGGL(k_corr_up, dim3(256), dim3(64), 0, stream, xref, xnb, bflow, bfeat, ws, bio);
    hipLaunchKernelGGL(k_conv0, dim3(256), dim3(256), 0, stream, inpT, wse + E_WT0, b0, hT);
    hipLaunchKernelGGL((k_conv32<2, 0>), dim3(256), dim3(256), 0, stream,
                       hT, wse + E_WT1, b1, t1T, (float*)nullptr, (const u16*)nullptr, bio);
    hipLaunchKernelGGL((k_conv32<2, 1>), dim3(256), dim3(256), 0, stream,
                       t1T, wse + E_WT2, b2, feaT, out, hT, bio);
    hipLaunchKernelGGL((k_conv32<1, 2>), dim3(256), dim3(256), 0, stream,
                       feaT, wse + E_WTF, bf, (u16*)nullptr, out, (const u16*)nullptr, bio);
  }
}